// Round 4
// baseline (704.172 us; speedup 1.0000x reference)
//
#include <hip/hip_runtime.h>
#include <math.h>

#define NUM_EMB 8192
#define DIM     64
#define NBATCH  4
#define NVOX    32768
#define TPB     256
#define CHUNK   256               // entries staged in LDS per iteration
#define HALF_E  (NUM_EMB / 2)     // each block scans one half of the codebook
#define THRESH  8.0f              // worst-case |d_hat - d2| <= ~5.8 for this data

// output layout (f32, concatenated in return order)
#define OFF_Q     0            // 32768*64
#define OFF_VQ    2097152
#define OFF_COMM  2097153
#define OFF_IDX   2097154      // 32768
#define OFF_PERP  2129922
#define OFF_ENT   2129923
#define OFF_UNIQ  2129924
#define OFF_UTIL  2129925

typedef __bf16 bf16x8 __attribute__((ext_vector_type(8)));
typedef float  f32x4  __attribute__((ext_vector_type(4)));

__device__ __forceinline__ unsigned short f2bf(float f) {   // RNE f32->bf16
    unsigned u = __float_as_uint(f);
    unsigned r = u + 0x7FFFu + ((u >> 16) & 1u);
    return (unsigned short)(r >> 16);
}

// monotone float -> sortable uint (all non-NaN)
__device__ __forceinline__ unsigned fmap(float f) {
    unsigned u = __float_as_uint(f);
    return (u & 0x80000000u) ? ~u : (u | 0x80000000u);
}

// fused: bf16 high-split of codebook + exact f32 row norms. wave per row? 4 rows/block.
__global__ void prep_kernel(const float* __restrict__ cb,
                            unsigned short* __restrict__ cbh,
                            float* __restrict__ cn) {
    int row = blockIdx.x * 4 + (threadIdx.x >> 6);
    int l   = threadIdx.x & 63;
    float f = cb[row * DIM + l];
    cbh[row * DIM + l] = f2bf(f);
    float s = f * f;
#pragma unroll
    for (int o = 32; o > 0; o >>= 1) s += __shfl_xor(s, o, 64);
    if (l == 0) cn[row] = s;
}

// Two-phase prune argmin:
//   A: approx dists via 1-product bf16 MFMA, per-row min m_hat (no indices)
//   B: bit-identical rescan; cells with d_hat <= m_hat+THRESH get an exact f32
//      distance (global cb/z, L2-hot) merged via packed u64 atomicMin
//      (exact value + lowest-index tiebreak).
__global__ __launch_bounds__(TPB) void argmin_prune_kernel(
        const float* __restrict__ z,
        const unsigned short* __restrict__ cbh,
        const float* __restrict__ cb,
        const float* __restrict__ cn,
        unsigned long long* __restrict__ merge) {
    __shared__ __align__(16) char lcb[CHUNK * 128];   // 32 KB, XOR-swizzled
    __shared__ float lcn[CHUNK];

    const int t  = threadIdx.x;
    const int l  = t & 63, w = t >> 6;
    const int lc = l & 15, lg = l >> 4;

    const int vb     = blockIdx.x >> 1;
    const int hf     = blockIdx.x & 1;
    const int ebase0 = hf * HALF_E;

    // A fragment: bf16 high-split of this wave's 16 z rows (validated layout, r3)
    const int arow = vb * 64 + w * 16 + lc;
    const float* zp = z + (size_t)arow * DIM + lg * 8;
    union U { bf16x8 v; unsigned short s[8]; };
    U Ah[2];
#pragma unroll
    for (int ks = 0; ks < 2; ++ks)
#pragma unroll
        for (int j = 0; j < 8; ++j) Ah[ks].s[j] = f2bf(zp[ks * 32 + j]);

    float m1[4] = {INFINITY, INFINITY, INFINITY, INFINITY};

    // ---------------- phase A: approx min ----------------
    for (int ch = 0; ch < HALF_E / CHUNK; ++ch) {
        const char* src = (const char*)cbh + (size_t)(ebase0 + ch * CHUNK) * 128;
#pragma unroll
        for (int j = 0; j < 8; ++j) {
            int off = (j * 256 + t) * 16;
            int swz = off ^ (((off >> 7) & 7) << 4);
            *(uint4*)(lcb + swz) = *(const uint4*)(src + off);
        }
        lcn[t] = cn[ebase0 + ch * CHUNK + t];
        __syncthreads();

#pragma unroll 4
        for (int tile = 0; tile < CHUNK / 16; ++tile) {
            int ecol = tile * 16 + lc;
            int a0 = ecol * 128 + lg * 16;
            int sx = (ecol & 7) << 4;
            bf16x8 b0 = *(const bf16x8*)(lcb + (a0 ^ sx));
            bf16x8 b1 = *(const bf16x8*)(lcb + ((a0 + 64) ^ sx));
            f32x4 acc = {0.f, 0.f, 0.f, 0.f};
            acc = __builtin_amdgcn_mfma_f32_16x16x32_bf16(Ah[0].v, b0, acc, 0, 0, 0);
            acc = __builtin_amdgcn_mfma_f32_16x16x32_bf16(Ah[1].v, b1, acc, 0, 0, 0);
            float cnv = lcn[ecol];
#pragma unroll
            for (int r = 0; r < 4; ++r)
                m1[r] = fminf(m1[r], fmaf(-2.f, acc[r], cnv));
        }
        __syncthreads();
    }

    // per-row min across the 16 column-lanes (all lanes receive result)
#pragma unroll
    for (int r = 0; r < 4; ++r) {
#pragma unroll
        for (int st = 1; st < 16; st <<= 1)
            m1[r] = fminf(m1[r], __shfl_xor(m1[r], st, 16));
        m1[r] += THRESH;
    }

    // ---------------- phase B: rescan + exact repair ----------------
    for (int ch = 0; ch < HALF_E / CHUNK; ++ch) {
        const char* src = (const char*)cbh + (size_t)(ebase0 + ch * CHUNK) * 128;
#pragma unroll
        for (int j = 0; j < 8; ++j) {
            int off = (j * 256 + t) * 16;
            int swz = off ^ (((off >> 7) & 7) << 4);
            *(uint4*)(lcb + swz) = *(const uint4*)(src + off);
        }
        lcn[t] = cn[ebase0 + ch * CHUNK + t];
        __syncthreads();

        for (int tile = 0; tile < CHUNK / 16; ++tile) {
            int ecol = tile * 16 + lc;
            int a0 = ecol * 128 + lg * 16;
            int sx = (ecol & 7) << 4;
            bf16x8 b0 = *(const bf16x8*)(lcb + (a0 ^ sx));
            bf16x8 b1 = *(const bf16x8*)(lcb + ((a0 + 64) ^ sx));
            f32x4 acc = {0.f, 0.f, 0.f, 0.f};
            acc = __builtin_amdgcn_mfma_f32_16x16x32_bf16(Ah[0].v, b0, acc, 0, 0, 0);
            acc = __builtin_amdgcn_mfma_f32_16x16x32_bf16(Ah[1].v, b1, acc, 0, 0, 0);
            float cnv = lcn[ecol];
            int eidx = ebase0 + ch * CHUNK + ecol;
#pragma unroll
            for (int r = 0; r < 4; ++r) {
                float dhat = fmaf(-2.f, acc[r], cnv);
                if (dhat <= m1[r]) {               // rare (~4 cells/voxel total)
                    int vrow = vb * 64 + w * 16 + lg * 4 + r;
                    const float4* crow = (const float4*)(cb + (size_t)eidx * DIM);
                    const float4* zrow = (const float4*)(z + (size_t)vrow * DIM);
                    float d0 = 0.f, d1 = 0.f, d2a = 0.f, d3 = 0.f;
#pragma unroll
                    for (int i = 0; i < DIM / 4; ++i) {
                        float4 c4 = crow[i];
                        float4 z4 = zrow[i];
                        d0 = fmaf(c4.x, z4.x, d0);
                        d1 = fmaf(c4.y, z4.y, d1);
                        d2a = fmaf(c4.z, z4.z, d2a);
                        d3 = fmaf(c4.w, z4.w, d3);
                    }
                    float dex = fmaf(-2.f, (d0 + d1) + (d2a + d3), cnv);
                    unsigned long long key =
                        ((unsigned long long)fmap(dex) << 32) | (unsigned)eidx;
                    atomicMin(&merge[vrow], key);
                }
            }
        }
        __syncthreads();
    }
}

__global__ void gather_kernel(const float* __restrict__ z, const int* __restrict__ zc,
        const float* __restrict__ cb, const unsigned long long* __restrict__ merge,
        float* __restrict__ out, unsigned* __restrict__ counts, float* __restrict__ sqsum) {
    int vox = blockIdx.x * blockDim.x + threadIdx.x;
    unsigned idx = (unsigned)(merge[vox] & 0xFFFFFFFFull);

    const float4* crow = (const float4*)(cb + (size_t)idx * DIM);
    const float4* zrow = (const float4*)(z + (size_t)vox * DIM);
    float4* qrow = (float4*)(out + OFF_Q + (size_t)vox * DIM);

    float s = 0.f;
#pragma unroll
    for (int i = 0; i < DIM / 4; ++i) {
        float4 c4 = crow[i];
        float4 z4 = zrow[i];
        float dx = z4.x - c4.x, dy = z4.y - c4.y;
        float dz = z4.z - c4.z, dw = z4.w - c4.w;
        s += dx * dx + dy * dy + dz * dz + dw * dw;
        qrow[i] = c4;
    }
    out[OFF_IDX + vox] = (float)idx;

    int b = zc[vox * 4];
    atomicAdd(&counts[b * NUM_EMB + idx], 1u);

#pragma unroll
    for (int o = 32; o > 0; o >>= 1) s += __shfl_down(s, o, 64);
    __shared__ float red[TPB / 64];
    if ((threadIdx.x & 63) == 0) red[threadIdx.x >> 6] = s;
    __syncthreads();
    if (threadIdx.x == 0) {
        float tt = red[0] + red[1] + red[2] + red[3];
        atomicAdd(sqsum, tt);
    }
}

__global__ void stats_kernel(const unsigned* __restrict__ counts, float* __restrict__ stats) {
    int b = blockIdx.x;
    const unsigned* c = counts + b * NUM_EMB;

    __shared__ float sred[TPB / 64];
    float nf = 0.f;
    for (int i = threadIdx.x; i < NUM_EMB; i += TPB) nf += (float)c[i];
#pragma unroll
    for (int o = 32; o > 0; o >>= 1) nf += __shfl_down(nf, o, 64);
    if ((threadIdx.x & 63) == 0) sred[threadIdx.x >> 6] = nf;
    __syncthreads();
    float n = sred[0] + sred[1] + sred[2] + sred[3];
    __syncthreads();

    float ent = 0.f, uniq = 0.f;
    for (int i = threadIdx.x; i < NUM_EMB; i += TPB) {
        unsigned ci = c[i];
        if (ci) {
            float p = (float)ci / n;
            ent -= p * logf(p + 1e-10f);
            uniq += 1.f;
        }
    }
#pragma unroll
    for (int o = 32; o > 0; o >>= 1) {
        ent  += __shfl_down(ent, o, 64);
        uniq += __shfl_down(uniq, o, 64);
    }
    __shared__ float e4[TPB / 64], u4[TPB / 64];
    if ((threadIdx.x & 63) == 0) { e4[threadIdx.x >> 6] = ent; u4[threadIdx.x >> 6] = uniq; }
    __syncthreads();
    if (threadIdx.x == 0) {
        stats[b]     = e4[0] + e4[1] + e4[2] + e4[3];
        stats[4 + b] = u4[0] + u4[1] + u4[2] + u4[3];
    }
}

__global__ void finalize_kernel(const float* __restrict__ stats,
                                const float* __restrict__ sqsum,
                                float* __restrict__ out) {
    float loss = *sqsum / (float)((size_t)NVOX * DIM);
    float ae = 0.f, ap = 0.f, au = 0.f;
#pragma unroll
    for (int b = 0; b < NBATCH; ++b) {
        ae += stats[b];
        ap += expf(stats[b]);
        au += stats[4 + b];
    }
    ae *= (1.f / NBATCH); ap *= (1.f / NBATCH); au *= (1.f / NBATCH);
    out[OFF_VQ]   = loss;
    out[OFF_COMM] = loss;
    out[OFF_PERP] = ap;
    out[OFF_ENT]  = ae;
    out[OFF_UNIQ] = au;
    out[OFF_UTIL] = au / (float)NUM_EMB * 100.f;
}

extern "C" void kernel_launch(void* const* d_in, const int* in_sizes, int n_in,
                              void* d_out, int out_size, void* d_ws, size_t ws_size,
                              hipStream_t stream) {
    const float* z  = (const float*)d_in[0];
    const int*   zc = (const int*)d_in[1];
    const float* cb = (const float*)d_in[2];
    float* out = (float*)d_out;
    char* ws = (char*)d_ws;

    // bf16 codebook split lives in the d_out Q-region as scratch (1 MB of 8 MB);
    // gather_kernel fully overwrites Q afterwards, so d_out validation is safe.
    unsigned short* cbh = (unsigned short*)(out + OFF_Q);

    unsigned long long* merge = (unsigned long long*)ws;   // 262144 B
    unsigned* counts = (unsigned*)(ws + 262144);           // 131072 B
    float*    cn     = (float*)(ws + 393216);              // 32768 B
    float*    sqsum  = (float*)(ws + 425984);              // 4 B
    float*    stats  = (float*)(ws + 425988);              // 32 B

    hipMemsetAsync(merge, 0xFF, 262144, stream);           // u64 max sentinel
    hipMemsetAsync(counts, 0, 131072, stream);
    hipMemsetAsync(sqsum, 0, 36, stream);

    prep_kernel<<<NUM_EMB / 4, TPB, 0, stream>>>(cb, cbh, cn);
    argmin_prune_kernel<<<(NVOX / 64) * 2, TPB, 0, stream>>>(z, cbh, cb, cn, merge);
    gather_kernel<<<NVOX / TPB, TPB, 0, stream>>>(z, zc, cb, merge, out, counts, sqsum);
    stats_kernel<<<NBATCH, TPB, 0, stream>>>(counts, stats);
    finalize_kernel<<<1, 1, 0, stream>>>(stats, sqsum, out);
}

// Round 5
// 633.585 us; speedup vs baseline: 1.1114x; 1.1114x over previous
//
#include <hip/hip_runtime.h>
#include <math.h>

#define NUM_EMB 8192
#define DIM     64
#define NBATCH  4
#define NVOX    32768
#define TPB     256
#define QENT    2048              // entries per block (quarter codebook)
#define CHUNK   128               // entries staged per iteration
#define CERT_EPS 0.015f           // v-space gap threshold (err bound ~3.2e-3)

// output layout (f32, concatenated in return order)
#define OFF_Q     0            // 32768*64
#define OFF_VQ    2097152
#define OFF_COMM  2097153
#define OFF_IDX   2097154      // 32768
#define OFF_PERP  2129922
#define OFF_ENT   2129923
#define OFF_UNIQ  2129924
#define OFF_UTIL  2129925

typedef __bf16 bf16x8 __attribute__((ext_vector_type(8)));
typedef float  f32x4  __attribute__((ext_vector_type(4)));

__device__ __forceinline__ unsigned short f2bf(float f) {   // RNE f32->bf16
    unsigned u = __float_as_uint(f);
    unsigned r = u + 0x7FFFu + ((u >> 16) & 1u);
    return (unsigned short)(r >> 16);
}
__device__ __forceinline__ float bf2f(unsigned short h) {
    return __uint_as_float(((unsigned)h) << 16);
}

// 2-way bf16 split of codebook + half-norms. 4 rows per 256-thr block.
__global__ void prep_kernel(const float* __restrict__ cb,
                            unsigned short* __restrict__ cbh,
                            unsigned short* __restrict__ cbm,
                            float* __restrict__ cnh) {
    int row = blockIdx.x * 4 + (threadIdx.x >> 6);
    int l   = threadIdx.x & 63;
    float f = cb[row * DIM + l];
    unsigned short hh = f2bf(f); float r1 = f - bf2f(hh);
    cbh[row * DIM + l] = hh;
    cbm[row * DIM + l] = f2bf(r1);
    float s = f * f;
#pragma unroll
    for (int o = 32; o > 0; o >>= 1) s += __shfl_xor(s, o, 64);
    if (l == 0) cnh[row] = 0.5f * s;
}

// Single-pass 3-product (hh,hm,mh) MFMA scan, tracking per-row (max1,idx,max2)
// of v = z.c - ||c||^2/2  (argmax v == argmin dist). 32 rows/wave (2 A-sets
// sharing B loads -> 12 MFMA per 4 ds_read_b128). Quarter codebook per block.
__global__ __launch_bounds__(TPB) void argmin_kernel(
        const float* __restrict__ z,
        const unsigned short* __restrict__ cbh,
        const unsigned short* __restrict__ cbm,
        const float* __restrict__ cnh,
        float4* __restrict__ res) {
    __shared__ __align__(16) char lbh[CHUNK * 128];
    __shared__ __align__(16) char lbm[CHUNK * 128];
    __shared__ float lcn[CHUNK];

    const int t  = threadIdx.x;
    const int l  = t & 63, w = t >> 6;
    const int lc = l & 15, lg = l >> 4;
    const int vb = blockIdx.x >> 2, qh = blockIdx.x & 3;
    const int ebase = qh * QENT;

    union U { bf16x8 v; unsigned short s[8]; };
    U Ah[2][2], Am[2][2];
#pragma unroll
    for (int set = 0; set < 2; ++set) {
        const float* zp = z + (size_t)(vb * 128 + w * 32 + set * 16 + lc) * DIM + lg * 8;
#pragma unroll
        for (int ks = 0; ks < 2; ++ks)
#pragma unroll
            for (int j = 0; j < 8; ++j) {
                float f = zp[ks * 32 + j];
                unsigned short hh = f2bf(f);
                Ah[set][ks].s[j] = hh;
                Am[set][ks].s[j] = f2bf(f - bf2f(hh));
            }
    }

    float m1[2][4], m2[2][4]; int ix[2][4];
#pragma unroll
    for (int set = 0; set < 2; ++set)
#pragma unroll
        for (int r = 0; r < 4; ++r) {
            m1[set][r] = -INFINITY; m2[set][r] = -INFINITY; ix[set][r] = 0;
        }

    for (int ch = 0; ch < QENT / CHUNK; ++ch) {
        const char* sh = (const char*)cbh + (size_t)(ebase + ch * CHUNK) * 128;
        const char* sm = (const char*)cbm + (size_t)(ebase + ch * CHUNK) * 128;
#pragma unroll
        for (int j = 0; j < 4; ++j) {            // XOR-swizzle (row&7)<<4
            int off = (j * 256 + t) * 16;
            int swz = off ^ (((off >> 7) & 7) << 4);
            *(uint4*)(lbh + swz) = *(const uint4*)(sh + off);
            *(uint4*)(lbm + swz) = *(const uint4*)(sm + off);
        }
        if (t < CHUNK) lcn[t] = cnh[ebase + ch * CHUNK + t];
        __syncthreads();

        for (int tile = 0; tile < CHUNK / 16; ++tile) {
            int ecol = tile * 16 + lc;
            int eidx = ebase + ch * CHUNK + ecol;
            float cnv = lcn[ecol];
            int a0 = ecol * 128 + lg * 16, sx = (ecol & 7) << 4;
            int s0 = a0 ^ sx, s1 = (a0 + 64) ^ sx;
            bf16x8 bh0 = *(const bf16x8*)(lbh + s0);
            bf16x8 bh1 = *(const bf16x8*)(lbh + s1);
            bf16x8 bm0 = *(const bf16x8*)(lbm + s0);
            bf16x8 bm1 = *(const bf16x8*)(lbm + s1);
#pragma unroll
            for (int set = 0; set < 2; ++set) {
                f32x4 a = {0.f, 0.f, 0.f, 0.f}, b = {0.f, 0.f, 0.f, 0.f};
                a = __builtin_amdgcn_mfma_f32_16x16x32_bf16(Ah[set][0].v, bh0, a, 0, 0, 0);
                a = __builtin_amdgcn_mfma_f32_16x16x32_bf16(Ah[set][0].v, bm0, a, 0, 0, 0);
                a = __builtin_amdgcn_mfma_f32_16x16x32_bf16(Am[set][0].v, bh0, a, 0, 0, 0);
                b = __builtin_amdgcn_mfma_f32_16x16x32_bf16(Ah[set][1].v, bh1, b, 0, 0, 0);
                b = __builtin_amdgcn_mfma_f32_16x16x32_bf16(Ah[set][1].v, bm1, b, 0, 0, 0);
                b = __builtin_amdgcn_mfma_f32_16x16x32_bf16(Am[set][1].v, bh1, b, 0, 0, 0);
#pragma unroll
                for (int r = 0; r < 4; ++r) {     // D: col=lc, row=lg*4+r (m89)
                    float v = (a[r] + b[r]) - cnv;
                    m2[set][r] = fmaxf(m2[set][r], fminf(m1[set][r], v));
                    if (v > m1[set][r]) { m1[set][r] = v; ix[set][r] = eidx; }
                }
            }
        }
        __syncthreads();
    }

    // reduce (max1,idx,max2) across the 16 column-lanes, lowest-idx tiebreak
#pragma unroll
    for (int set = 0; set < 2; ++set)
#pragma unroll
        for (int r = 0; r < 4; ++r) {
            float v1 = m1[set][r], v2 = m2[set][r]; int i1 = ix[set][r];
#pragma unroll
            for (int st = 1; st < 16; st <<= 1) {
                float o1 = __shfl_xor(v1, st, 16);
                float o2 = __shfl_xor(v2, st, 16);
                int   oi = __shfl_xor(i1, st, 16);
                float mn = fminf(v1, o1);
                v2 = fmaxf(fmaxf(v2, o2), mn);
                if (o1 > v1 || (o1 == v1 && oi < i1)) { v1 = o1; i1 = oi; }
            }
            if (lc == 0) {
                int vox = vb * 128 + w * 32 + set * 16 + lg * 4 + r;
                res[(size_t)qh * NVOX + vox] =
                    make_float4(v1, v2, __int_as_float(i1), 0.f);
            }
        }
}

// combine 4 quarter-results -> packed (idx | flag<<31) into the IDX slot
__global__ void combine_kernel(const float4* __restrict__ res, float* __restrict__ out) {
    int vox = blockIdx.x * blockDim.x + threadIdx.x;
    float v1 = -INFINITY, v2 = -INFINITY; int idx = 0;
#pragma unroll
    for (int h = 0; h < 4; ++h) {
        float4 t4 = res[(size_t)h * NVOX + vox];
        float a1 = t4.x, a2 = t4.y; int ai = __float_as_int(t4.z);
        float mn = fminf(v1, a1);
        v2 = fmaxf(fmaxf(v2, a2), mn);
        if (a1 > v1) { v1 = a1; idx = ai; }   // strict >: earlier quarter wins ties
    }
    unsigned flag = (v1 - v2 < CERT_EPS) ? 0x80000000u : 0u;
    ((unsigned*)out)[OFF_IDX + vox] = (unsigned)idx | flag;
}

__global__ void gather_kernel(const float* __restrict__ z, const int* __restrict__ zc,
        const float* __restrict__ cb, float* __restrict__ out,
        unsigned* __restrict__ counts, float* __restrict__ sqsum,
        unsigned* __restrict__ list, unsigned* __restrict__ lcount) {
    int vox = blockIdx.x * blockDim.x + threadIdx.x;
    unsigned pk = ((unsigned*)out)[OFF_IDX + vox];
    float s = 0.f;
    if (pk & 0x80000000u) {
        unsigned pos = atomicAdd(lcount, 1u);
        list[pos] = vox;                       // repair kernel finishes this row
    } else {
        unsigned idx = pk;
        const float4* crow = (const float4*)(cb + (size_t)idx * DIM);
        const float4* zrow = (const float4*)(z + (size_t)vox * DIM);
        float4* qrow = (float4*)(out + OFF_Q + (size_t)vox * DIM);
#pragma unroll
        for (int i = 0; i < DIM / 4; ++i) {
            float4 c4 = crow[i];
            float4 z4 = zrow[i];
            float dx = z4.x - c4.x, dy = z4.y - c4.y;
            float dz = z4.z - c4.z, dw = z4.w - c4.w;
            s += dx * dx + dy * dy + dz * dz + dw * dw;
            qrow[i] = c4;
        }
        out[OFF_IDX + vox] = (float)idx;
        atomicAdd(&counts[zc[vox * 4] * NUM_EMB + idx], 1u);
    }
#pragma unroll
    for (int o = 32; o > 0; o >>= 1) s += __shfl_down(s, o, 64);
    __shared__ float red[TPB / 64];
    if ((threadIdx.x & 63) == 0) red[threadIdx.x >> 6] = s;
    __syncthreads();
    if (threadIdx.x == 0)
        atomicAdd(sqsum, red[0] + red[1] + red[2] + red[3]);
}

// exact f32 argmin for flagged rows; one wave per row, grid-stride over list
__global__ void repair_kernel(const float* __restrict__ z, const int* __restrict__ zc,
        const float* __restrict__ cb, const unsigned* __restrict__ list,
        const unsigned* __restrict__ lcount, float* __restrict__ out,
        unsigned* __restrict__ counts, float* __restrict__ sqsum) {
    int wid = (blockIdx.x * blockDim.x + threadIdx.x) >> 6;
    int l   = threadIdx.x & 63;
    int n   = (int)*lcount;
    int nw  = (gridDim.x * blockDim.x) >> 6;
    for (int k = wid; k < n; k += nw) {
        int vox = list[k];
        const float* zr = z + (size_t)vox * DIM;    // wave-uniform -> broadcast
        float m = INFINITY; int mi = 0;
        for (int e = l; e < NUM_EMB; e += 64) {
            const float4* cr = (const float4*)(cb + (size_t)e * DIM);
            float s0 = 0.f, s1 = 0.f, s2 = 0.f, s3 = 0.f;
#pragma unroll
            for (int i = 0; i < DIM / 4; ++i) {
                float4 c4 = cr[i];
                float dx = zr[4 * i + 0] - c4.x, dy = zr[4 * i + 1] - c4.y;
                float dz = zr[4 * i + 2] - c4.z, dw = zr[4 * i + 3] - c4.w;
                s0 = fmaf(dx, dx, s0); s1 = fmaf(dy, dy, s1);
                s2 = fmaf(dz, dz, s2); s3 = fmaf(dw, dw, s3);
            }
            float d = (s0 + s1) + (s2 + s3);
            if (d < m) { m = d; mi = e; }           // ascending e: lowest-idx ties
        }
#pragma unroll
        for (int st = 32; st > 0; st >>= 1) {
            float om = __shfl_xor(m, st, 64);
            int   oi = __shfl_xor(mi, st, 64);
            if (om < m || (om == m && oi < mi)) { m = om; mi = oi; }
        }
        float cv = cb[(size_t)mi * DIM + l];
        float zv = zr[l];
        out[OFF_Q + (size_t)vox * DIM + l] = cv;
        float df = zv - cv;
        float s = df * df;
#pragma unroll
        for (int st = 32; st > 0; st >>= 1) s += __shfl_xor(s, st, 64);
        if (l == 0) {
            out[OFF_IDX + vox] = (float)mi;
            atomicAdd(&counts[zc[vox * 4] * NUM_EMB + mi], 1u);
            atomicAdd(sqsum, s);
        }
    }
}

__global__ void stats_kernel(const unsigned* __restrict__ counts, float* __restrict__ stats) {
    int b = blockIdx.x;
    const unsigned* c = counts + b * NUM_EMB;

    __shared__ float sred[TPB / 64];
    float nf = 0.f;
    for (int i = threadIdx.x; i < NUM_EMB; i += TPB) nf += (float)c[i];
#pragma unroll
    for (int o = 32; o > 0; o >>= 1) nf += __shfl_down(nf, o, 64);
    if ((threadIdx.x & 63) == 0) sred[threadIdx.x >> 6] = nf;
    __syncthreads();
    float n = sred[0] + sred[1] + sred[2] + sred[3];
    __syncthreads();

    float ent = 0.f, uniq = 0.f;
    for (int i = threadIdx.x; i < NUM_EMB; i += TPB) {
        unsigned ci = c[i];
        if (ci) {
            float p = (float)ci / n;
            ent -= p * logf(p + 1e-10f);
            uniq += 1.f;
        }
    }
#pragma unroll
    for (int o = 32; o > 0; o >>= 1) {
        ent  += __shfl_down(ent, o, 64);
        uniq += __shfl_down(uniq, o, 64);
    }
    __shared__ float e4[TPB / 64], u4[TPB / 64];
    if ((threadIdx.x & 63) == 0) { e4[threadIdx.x >> 6] = ent; u4[threadIdx.x >> 6] = uniq; }
    __syncthreads();
    if (threadIdx.x == 0) {
        stats[b]     = e4[0] + e4[1] + e4[2] + e4[3];
        stats[4 + b] = u4[0] + u4[1] + u4[2] + u4[3];
    }
}

__global__ void finalize_kernel(const float* __restrict__ stats,
                                const float* __restrict__ sqsum,
                                float* __restrict__ out) {
    float loss = *sqsum / (float)((size_t)NVOX * DIM);
    float ae = 0.f, ap = 0.f, au = 0.f;
#pragma unroll
    for (int b = 0; b < NBATCH; ++b) {
        ae += stats[b];
        ap += expf(stats[b]);
        au += stats[4 + b];
    }
    ae *= (1.f / NBATCH); ap *= (1.f / NBATCH); au *= (1.f / NBATCH);
    out[OFF_VQ]   = loss;
    out[OFF_COMM] = loss;
    out[OFF_PERP] = ap;
    out[OFF_ENT]  = ae;
    out[OFF_UNIQ] = au;
    out[OFF_UTIL] = au / (float)NUM_EMB * 100.f;
}

extern "C" void kernel_launch(void* const* d_in, const int* in_sizes, int n_in,
                              void* d_out, int out_size, void* d_ws, size_t ws_size,
                              hipStream_t stream) {
    const float* z  = (const float*)d_in[0];
    const int*   zc = (const int*)d_in[1];
    const float* cb = (const float*)d_in[2];
    float* out = (float*)d_out;
    char* ws = (char*)d_ws;

    // scratch in the d_out Q-region (8MB): cbh 1MB | cbm 1MB | res 2MB.
    // prep writes cbh/cbm; argmin reads them, writes res; combine reads res,
    // writes packed IDX; gather/repair then overwrite all of Q. No overlap of
    // concurrent reader/writer regions at any stage.
    unsigned short* cbh = (unsigned short*)out;
    unsigned short* cbm = cbh + NUM_EMB * DIM;
    float4* res = (float4*)(out + 524288);

    unsigned* counts = (unsigned*)ws;                  // 131072 B
    unsigned* list   = (unsigned*)(ws + 131072);       // 131072 B
    unsigned* lcount = (unsigned*)(ws + 262144);       // 4 B
    float*    sqsum  = (float*)(ws + 262148);          // 4 B
    float*    stats  = (float*)(ws + 262152);          // 32 B
    float*    cnh    = (float*)(ws + 262184);          // 32768 B

    hipMemsetAsync(counts, 0, 131072, stream);
    hipMemsetAsync(lcount, 0, 40, stream);             // lcount + sqsum + stats

    prep_kernel<<<NUM_EMB / 4, TPB, 0, stream>>>(cb, cbh, cbm, cnh);
    argmin_kernel<<<(NVOX / 128) * 4, TPB, 0, stream>>>(z, cbh, cbm, cnh, res);
    combine_kernel<<<NVOX / TPB, TPB, 0, stream>>>(res, out);
    gather_kernel<<<NVOX / TPB, TPB, 0, stream>>>(z, zc, cb, out, counts, sqsum,
                                                  list, lcount);
    repair_kernel<<<64, TPB, 0, stream>>>(z, zc, cb, list, lcount, out, counts, sqsum);
    stats_kernel<<<NBATCH, TPB, 0, stream>>>(counts, stats);
    finalize_kernel<<<1, 1, 0, stream>>>(stats, sqsum, out);
}

// Round 6
// 608.559 us; speedup vs baseline: 1.1571x; 1.0411x over previous
//
#include <hip/hip_runtime.h>
#include <math.h>

#define NUM_EMB 8192
#define DIM     64
#define NBATCH  4
#define NVOX    32768
#define TPB     256
#define QENT    2048              // entries per block (quarter codebook)
#define CHUNK   128               // entries staged per iteration
#define CERT_EPS 0.015f           // v-space gap threshold (err bound ~3.2e-3)

// output layout (f32, concatenated in return order)
#define OFF_Q     0            // 32768*64
#define OFF_VQ    2097152
#define OFF_COMM  2097153
#define OFF_IDX   2097154      // 32768
#define OFF_PERP  2129922
#define OFF_ENT   2129923
#define OFF_UNIQ  2129924
#define OFF_UTIL  2129925

typedef __bf16 bf16x8 __attribute__((ext_vector_type(8)));
typedef float  f32x4  __attribute__((ext_vector_type(4)));

__device__ __forceinline__ unsigned short f2bf(float f) {   // RNE f32->bf16
    unsigned u = __float_as_uint(f);
    unsigned r = u + 0x7FFFu + ((u >> 16) & 1u);
    return (unsigned short)(r >> 16);
}
__device__ __forceinline__ float bf2f(unsigned short h) {
    return __uint_as_float(((unsigned)h) << 16);
}

// 2-way bf16 split of codebook + half-norms. 4 rows per 256-thr block.
__global__ void prep_kernel(const float* __restrict__ cb,
                            unsigned short* __restrict__ cbh,
                            unsigned short* __restrict__ cbm,
                            float* __restrict__ cnh) {
    int row = blockIdx.x * 4 + (threadIdx.x >> 6);
    int l   = threadIdx.x & 63;
    float f = cb[row * DIM + l];
    unsigned short hh = f2bf(f); float r1 = f - bf2f(hh);
    cbh[row * DIM + l] = hh;
    cbm[row * DIM + l] = f2bf(r1);
    float s = f * f;
#pragma unroll
    for (int o = 32; o > 0; o >>= 1) s += __shfl_xor(s, o, 64);
    if (l == 0) cnh[row] = 0.5f * s;
}

// Single-pass 3-product (hh,hm,mh) MFMA scan, tracking per-row (max1,idx,max2)
// of v = z.c - ||c||^2/2  (argmax v == argmin dist). 32 rows/wave (2 A-sets
// sharing B loads -> 12 MFMA per 4 ds_read_b128). Quarter codebook per block.
__global__ __launch_bounds__(TPB) void argmin_kernel(
        const float* __restrict__ z,
        const unsigned short* __restrict__ cbh,
        const unsigned short* __restrict__ cbm,
        const float* __restrict__ cnh,
        float4* __restrict__ res) {
    __shared__ __align__(16) char lbh[CHUNK * 128];
    __shared__ __align__(16) char lbm[CHUNK * 128];
    __shared__ float lcn[CHUNK];

    const int t  = threadIdx.x;
    const int l  = t & 63, w = t >> 6;
    const int lc = l & 15, lg = l >> 4;
    const int vb = blockIdx.x >> 2, qh = blockIdx.x & 3;
    const int ebase = qh * QENT;

    union U { bf16x8 v; unsigned short s[8]; };
    U Ah[2][2], Am[2][2];
#pragma unroll
    for (int set = 0; set < 2; ++set) {
        const float* zp = z + (size_t)(vb * 128 + w * 32 + set * 16 + lc) * DIM + lg * 8;
#pragma unroll
        for (int ks = 0; ks < 2; ++ks)
#pragma unroll
            for (int j = 0; j < 8; ++j) {
                float f = zp[ks * 32 + j];
                unsigned short hh = f2bf(f);
                Ah[set][ks].s[j] = hh;
                Am[set][ks].s[j] = f2bf(f - bf2f(hh));
            }
    }

    float m1[2][4], m2[2][4]; int ix[2][4];
#pragma unroll
    for (int set = 0; set < 2; ++set)
#pragma unroll
        for (int r = 0; r < 4; ++r) {
            m1[set][r] = -INFINITY; m2[set][r] = -INFINITY; ix[set][r] = 0;
        }

    for (int ch = 0; ch < QENT / CHUNK; ++ch) {
        const char* sh = (const char*)cbh + (size_t)(ebase + ch * CHUNK) * 128;
        const char* sm = (const char*)cbm + (size_t)(ebase + ch * CHUNK) * 128;
#pragma unroll
        for (int j = 0; j < 4; ++j) {            // XOR-swizzle (row&7)<<4
            int off = (j * 256 + t) * 16;
            int swz = off ^ (((off >> 7) & 7) << 4);
            *(uint4*)(lbh + swz) = *(const uint4*)(sh + off);
            *(uint4*)(lbm + swz) = *(const uint4*)(sm + off);
        }
        if (t < CHUNK) lcn[t] = cnh[ebase + ch * CHUNK + t];
        __syncthreads();

        for (int tile = 0; tile < CHUNK / 16; ++tile) {
            int ecol = tile * 16 + lc;
            int eidx = ebase + ch * CHUNK + ecol;
            float cnv = lcn[ecol];
            int a0 = ecol * 128 + lg * 16, sx = (ecol & 7) << 4;
            int s0 = a0 ^ sx, s1 = (a0 + 64) ^ sx;
            bf16x8 bh0 = *(const bf16x8*)(lbh + s0);
            bf16x8 bh1 = *(const bf16x8*)(lbh + s1);
            bf16x8 bm0 = *(const bf16x8*)(lbm + s0);
            bf16x8 bm1 = *(const bf16x8*)(lbm + s1);
#pragma unroll
            for (int set = 0; set < 2; ++set) {
                f32x4 a = {0.f, 0.f, 0.f, 0.f}, b = {0.f, 0.f, 0.f, 0.f};
                a = __builtin_amdgcn_mfma_f32_16x16x32_bf16(Ah[set][0].v, bh0, a, 0, 0, 0);
                a = __builtin_amdgcn_mfma_f32_16x16x32_bf16(Ah[set][0].v, bm0, a, 0, 0, 0);
                a = __builtin_amdgcn_mfma_f32_16x16x32_bf16(Am[set][0].v, bh0, a, 0, 0, 0);
                b = __builtin_amdgcn_mfma_f32_16x16x32_bf16(Ah[set][1].v, bh1, b, 0, 0, 0);
                b = __builtin_amdgcn_mfma_f32_16x16x32_bf16(Ah[set][1].v, bm1, b, 0, 0, 0);
                b = __builtin_amdgcn_mfma_f32_16x16x32_bf16(Am[set][1].v, bh1, b, 0, 0, 0);
#pragma unroll
                for (int r = 0; r < 4; ++r) {     // D: col=lc, row=lg*4+r (m89)
                    float v = (a[r] + b[r]) - cnv;
                    m2[set][r] = fmaxf(m2[set][r], fminf(m1[set][r], v));
                    if (v > m1[set][r]) { m1[set][r] = v; ix[set][r] = eidx; }
                }
            }
        }
        __syncthreads();
    }

    // reduce (max1,idx,max2) across the 16 column-lanes, lowest-idx tiebreak
#pragma unroll
    for (int set = 0; set < 2; ++set)
#pragma unroll
        for (int r = 0; r < 4; ++r) {
            float v1 = m1[set][r], v2 = m2[set][r]; int i1 = ix[set][r];
#pragma unroll
            for (int st = 1; st < 16; st <<= 1) {
                float o1 = __shfl_xor(v1, st, 16);
                float o2 = __shfl_xor(v2, st, 16);
                int   oi = __shfl_xor(i1, st, 16);
                float mn = fminf(v1, o1);
                v2 = fmaxf(fmaxf(v2, o2), mn);
                if (o1 > v1 || (o1 == v1 && oi < i1)) { v1 = o1; i1 = oi; }
            }
            if (lc == 0) {
                int vox = vb * 128 + w * 32 + set * 16 + lg * 4 + r;
                res[(size_t)qh * NVOX + vox] =
                    make_float4(v1, v2, __int_as_float(i1), 0.f);
            }
        }
}

// combine 4 quarter-results -> packed (idx | flag<<31) into the IDX slot
__global__ void combine_kernel(const float4* __restrict__ res, float* __restrict__ out) {
    int vox = blockIdx.x * blockDim.x + threadIdx.x;
    float v1 = -INFINITY, v2 = -INFINITY; int idx = 0;
#pragma unroll
    for (int h = 0; h < 4; ++h) {
        float4 t4 = res[(size_t)h * NVOX + vox];
        float a1 = t4.x, a2 = t4.y; int ai = __float_as_int(t4.z);
        float mn = fminf(v1, a1);
        v2 = fmaxf(fmaxf(v2, a2), mn);
        if (a1 > v1) { v1 = a1; idx = ai; }   // strict >: earlier quarter wins ties
    }
    unsigned flag = (v1 - v2 < CERT_EPS) ? 0x80000000u : 0u;
    ((unsigned*)out)[OFF_IDX + vox] = (unsigned)idx | flag;
}

__global__ void gather_kernel(const float* __restrict__ z, const int* __restrict__ zc,
        const float* __restrict__ cb, float* __restrict__ out,
        unsigned* __restrict__ counts, float* __restrict__ sqsum,
        unsigned* __restrict__ list, unsigned* __restrict__ lcount) {
    int vox = blockIdx.x * blockDim.x + threadIdx.x;
    unsigned pk = ((unsigned*)out)[OFF_IDX + vox];
    float s = 0.f;
    if (pk & 0x80000000u) {
        unsigned pos = atomicAdd(lcount, 1u);
        list[pos] = vox;                       // repair kernel finishes this row
    } else {
        unsigned idx = pk;
        const float4* crow = (const float4*)(cb + (size_t)idx * DIM);
        const float4* zrow = (const float4*)(z + (size_t)vox * DIM);
        float4* qrow = (float4*)(out + OFF_Q + (size_t)vox * DIM);
#pragma unroll
        for (int i = 0; i < DIM / 4; ++i) {
            float4 c4 = crow[i];
            float4 z4 = zrow[i];
            float dx = z4.x - c4.x, dy = z4.y - c4.y;
            float dz = z4.z - c4.z, dw = z4.w - c4.w;
            s += dx * dx + dy * dy + dz * dz + dw * dw;
            qrow[i] = c4;
        }
        out[OFF_IDX + vox] = (float)idx;
        atomicAdd(&counts[zc[vox * 4] * NUM_EMB + idx], 1u);
    }
#pragma unroll
    for (int o = 32; o > 0; o >>= 1) s += __shfl_down(s, o, 64);
    __shared__ float red[TPB / 64];
    if ((threadIdx.x & 63) == 0) red[threadIdx.x >> 6] = s;
    __syncthreads();
    if (threadIdx.x == 0)
        atomicAdd(sqsum, red[0] + red[1] + red[2] + red[3]);
}

// exact f32 argmin for flagged rows; one wave per row, grid-stride over list.
// COALESCED layout (r5 fix): 4 entries/iteration; lane l -> entry g*4+(l>>4),
// float4 slice (l&15); wave's byte addr = g*1024 + l*16 (one 1KB contiguous
// load/instr vs r5's 64-distinct-lines-per-instr divergence = 455us).
__global__ void repair_kernel(const float* __restrict__ z, const int* __restrict__ zc,
        const float* __restrict__ cb, const unsigned* __restrict__ list,
        const unsigned* __restrict__ lcount, float* __restrict__ out,
        unsigned* __restrict__ counts, float* __restrict__ sqsum) {
    int wid = (blockIdx.x * blockDim.x + threadIdx.x) >> 6;
    int l   = threadIdx.x & 63;
    int n   = (int)*lcount;
    int nw  = (gridDim.x * blockDim.x) >> 6;
    int sub = l & 15;                 // float4 slice within entry row
    int ent = l >> 4;                 // entry within 4-entry group
    for (int k = wid; k < n; k += nw) {
        int vox = list[k];
        float4 z4 = ((const float4*)(z + (size_t)vox * DIM))[sub];
        float m = INFINITY; int mi = 0;
        for (int g = 0; g < NUM_EMB / 4; ++g) {
            int e = g * 4 + ent;
            float4 c4 = ((const float4*)(cb + (size_t)e * DIM))[sub];
            float dx = z4.x - c4.x, dy = z4.y - c4.y;
            float dz = z4.z - c4.z, dw = z4.w - c4.w;
            float d = fmaf(dx, dx, fmaf(dy, dy, fmaf(dz, dz, dw * dw)));
#pragma unroll
            for (int st = 1; st < 16; st <<= 1)     // reduce over 16 sub-lanes
                d += __shfl_xor(d, st, 16);
            if (d < m) { m = d; mi = e; }           // e ascending: lowest-idx ties
        }
#pragma unroll
        for (int st = 32; st > 0; st >>= 1) {
            float om = __shfl_xor(m, st, 64);
            int   oi = __shfl_xor(mi, st, 64);
            if (om < m || (om == m && oi < mi)) { m = om; mi = oi; }
        }
        float cv = cb[(size_t)mi * DIM + l];
        float zv = z[(size_t)vox * DIM + l];
        out[OFF_Q + (size_t)vox * DIM + l] = cv;
        float df = zv - cv;
        float s = df * df;
#pragma unroll
        for (int st = 32; st > 0; st >>= 1) s += __shfl_xor(s, st, 64);
        if (l == 0) {
            out[OFF_IDX + vox] = (float)mi;
            atomicAdd(&counts[zc[vox * 4] * NUM_EMB + mi], 1u);
            atomicAdd(sqsum, s);
        }
    }
}

__global__ void stats_kernel(const unsigned* __restrict__ counts, float* __restrict__ stats) {
    int b = blockIdx.x;
    const unsigned* c = counts + b * NUM_EMB;

    __shared__ float sred[TPB / 64];
    float nf = 0.f;
    for (int i = threadIdx.x; i < NUM_EMB; i += TPB) nf += (float)c[i];
#pragma unroll
    for (int o = 32; o > 0; o >>= 1) nf += __shfl_down(nf, o, 64);
    if ((threadIdx.x & 63) == 0) sred[threadIdx.x >> 6] = nf;
    __syncthreads();
    float n = sred[0] + sred[1] + sred[2] + sred[3];
    __syncthreads();

    float ent = 0.f, uniq = 0.f;
    for (int i = threadIdx.x; i < NUM_EMB; i += TPB) {
        unsigned ci = c[i];
        if (ci) {
            float p = (float)ci / n;
            ent -= p * logf(p + 1e-10f);
            uniq += 1.f;
        }
    }
#pragma unroll
    for (int o = 32; o > 0; o >>= 1) {
        ent  += __shfl_down(ent, o, 64);
        uniq += __shfl_down(uniq, o, 64);
    }
    __shared__ float e4[TPB / 64], u4[TPB / 64];
    if ((threadIdx.x & 63) == 0) { e4[threadIdx.x >> 6] = ent; u4[threadIdx.x >> 6] = uniq; }
    __syncthreads();
    if (threadIdx.x == 0) {
        stats[b]     = e4[0] + e4[1] + e4[2] + e4[3];
        stats[4 + b] = u4[0] + u4[1] + u4[2] + u4[3];
    }
}

__global__ void finalize_kernel(const float* __restrict__ stats,
                                const float* __restrict__ sqsum,
                                float* __restrict__ out) {
    float loss = *sqsum / (float)((size_t)NVOX * DIM);
    float ae = 0.f, ap = 0.f, au = 0.f;
#pragma unroll
    for (int b = 0; b < NBATCH; ++b) {
        ae += stats[b];
        ap += expf(stats[b]);
        au += stats[4 + b];
    }
    ae *= (1.f / NBATCH); ap *= (1.f / NBATCH); au *= (1.f / NBATCH);
    out[OFF_VQ]   = loss;
    out[OFF_COMM] = loss;
    out[OFF_PERP] = ap;
    out[OFF_ENT]  = ae;
    out[OFF_UNIQ] = au;
    out[OFF_UTIL] = au / (float)NUM_EMB * 100.f;
}

extern "C" void kernel_launch(void* const* d_in, const int* in_sizes, int n_in,
                              void* d_out, int out_size, void* d_ws, size_t ws_size,
                              hipStream_t stream) {
    const float* z  = (const float*)d_in[0];
    const int*   zc = (const int*)d_in[1];
    const float* cb = (const float*)d_in[2];
    float* out = (float*)d_out;
    char* ws = (char*)d_ws;

    // scratch in the d_out Q-region (8MB): cbh 1MB | cbm 1MB | res 2MB.
    unsigned short* cbh = (unsigned short*)out;
    unsigned short* cbm = cbh + NUM_EMB * DIM;
    float4* res = (float4*)(out + 524288);

    unsigned* counts = (unsigned*)ws;                  // 131072 B
    unsigned* list   = (unsigned*)(ws + 131072);       // 131072 B
    unsigned* lcount = (unsigned*)(ws + 262144);       // 4 B
    float*    sqsum  = (float*)(ws + 262148);          // 4 B
    float*    stats  = (float*)(ws + 262152);          // 32 B
    float*    cnh    = (float*)(ws + 262184);          // 32768 B

    hipMemsetAsync(counts, 0, 131072, stream);
    hipMemsetAsync(lcount, 0, 40, stream);             // lcount + sqsum + stats

    prep_kernel<<<NUM_EMB / 4, TPB, 0, stream>>>(cb, cbh, cbm, cnh);
    argmin_kernel<<<(NVOX / 128) * 4, TPB, 0, stream>>>(z, cbh, cbm, cnh, res);
    combine_kernel<<<NVOX / TPB, TPB, 0, stream>>>(res, out);
    gather_kernel<<<NVOX / TPB, TPB, 0, stream>>>(z, zc, cb, out, counts, sqsum,
                                                  list, lcount);
    repair_kernel<<<256, TPB, 0, stream>>>(z, zc, cb, list, lcount, out, counts, sqsum);
    stats_kernel<<<NBATCH, TPB, 0, stream>>>(counts, stats);
    finalize_kernel<<<1, 1, 0, stream>>>(stats, sqsum, out);
}

// Round 7
// 241.084 us; speedup vs baseline: 2.9209x; 2.5243x over previous
//
#include <hip/hip_runtime.h>
#include <math.h>

#define NUM_EMB 8192
#define DIM     64
#define NBATCH  4
#define NVOX    32768
#define TPB     256
#define QENT    2048              // entries per block (quarter codebook)
#define CHUNK   128               // entries staged per iteration
#define CERT_EPS 0.015f           // v-space gap threshold (err bound ~3.2e-3)
#define RCH     512               // repair: entries per (row,chunk) work item

// output layout (f32, concatenated in return order)
#define OFF_Q     0            // 32768*64
#define OFF_VQ    2097152
#define OFF_COMM  2097153
#define OFF_IDX   2097154      // 32768
#define OFF_PERP  2129922
#define OFF_ENT   2129923
#define OFF_UNIQ  2129924
#define OFF_UTIL  2129925

typedef __bf16 bf16x8 __attribute__((ext_vector_type(8)));
typedef float  f32x4  __attribute__((ext_vector_type(4)));

__device__ __forceinline__ unsigned short f2bf(float f) {   // RNE f32->bf16
    unsigned u = __float_as_uint(f);
    unsigned r = u + 0x7FFFu + ((u >> 16) & 1u);
    return (unsigned short)(r >> 16);
}
__device__ __forceinline__ float bf2f(unsigned short h) {
    return __uint_as_float(((unsigned)h) << 16);
}
// monotone float -> sortable uint (non-NaN)
__device__ __forceinline__ unsigned fmap(float f) {
    unsigned u = __float_as_uint(f);
    return (u & 0x80000000u) ? ~u : (u | 0x80000000u);
}

// 2-way bf16 split of codebook + half-norms. 4 rows per 256-thr block.
__global__ void prep_kernel(const float* __restrict__ cb,
                            unsigned short* __restrict__ cbh,
                            unsigned short* __restrict__ cbm,
                            float* __restrict__ cnh) {
    int row = blockIdx.x * 4 + (threadIdx.x >> 6);
    int l   = threadIdx.x & 63;
    float f = cb[row * DIM + l];
    unsigned short hh = f2bf(f); float r1 = f - bf2f(hh);
    cbh[row * DIM + l] = hh;
    cbm[row * DIM + l] = f2bf(r1);
    float s = f * f;
#pragma unroll
    for (int o = 32; o > 0; o >>= 1) s += __shfl_xor(s, o, 64);
    if (l == 0) cnh[row] = 0.5f * s;
}

// Single-pass 3-product (hh,hm,mh) MFMA scan, tracking per-row (max1,idx,max2)
// of v = z.c - ||c||^2/2  (argmax v == argmin dist). 32 rows/wave.
__global__ __launch_bounds__(TPB) void argmin_kernel(
        const float* __restrict__ z,
        const unsigned short* __restrict__ cbh,
        const unsigned short* __restrict__ cbm,
        const float* __restrict__ cnh,
        float4* __restrict__ res) {
    __shared__ __align__(16) char lbh[CHUNK * 128];
    __shared__ __align__(16) char lbm[CHUNK * 128];
    __shared__ float lcn[CHUNK];

    const int t  = threadIdx.x;
    const int l  = t & 63, w = t >> 6;
    const int lc = l & 15, lg = l >> 4;
    const int vb = blockIdx.x >> 2, qh = blockIdx.x & 3;
    const int ebase = qh * QENT;

    union U { bf16x8 v; unsigned short s[8]; };
    U Ah[2][2], Am[2][2];
#pragma unroll
    for (int set = 0; set < 2; ++set) {
        const float* zp = z + (size_t)(vb * 128 + w * 32 + set * 16 + lc) * DIM + lg * 8;
#pragma unroll
        for (int ks = 0; ks < 2; ++ks)
#pragma unroll
            for (int j = 0; j < 8; ++j) {
                float f = zp[ks * 32 + j];
                unsigned short hh = f2bf(f);
                Ah[set][ks].s[j] = hh;
                Am[set][ks].s[j] = f2bf(f - bf2f(hh));
            }
    }

    float m1[2][4], m2[2][4]; int ix[2][4];
#pragma unroll
    for (int set = 0; set < 2; ++set)
#pragma unroll
        for (int r = 0; r < 4; ++r) {
            m1[set][r] = -INFINITY; m2[set][r] = -INFINITY; ix[set][r] = 0;
        }

    for (int ch = 0; ch < QENT / CHUNK; ++ch) {
        const char* sh = (const char*)cbh + (size_t)(ebase + ch * CHUNK) * 128;
        const char* sm = (const char*)cbm + (size_t)(ebase + ch * CHUNK) * 128;
#pragma unroll
        for (int j = 0; j < 4; ++j) {            // XOR-swizzle (row&7)<<4
            int off = (j * 256 + t) * 16;
            int swz = off ^ (((off >> 7) & 7) << 4);
            *(uint4*)(lbh + swz) = *(const uint4*)(sh + off);
            *(uint4*)(lbm + swz) = *(const uint4*)(sm + off);
        }
        if (t < CHUNK) lcn[t] = cnh[ebase + ch * CHUNK + t];
        __syncthreads();

        for (int tile = 0; tile < CHUNK / 16; ++tile) {
            int ecol = tile * 16 + lc;
            int eidx = ebase + ch * CHUNK + ecol;
            float cnv = lcn[ecol];
            int a0 = ecol * 128 + lg * 16, sx = (ecol & 7) << 4;
            int s0 = a0 ^ sx, s1 = (a0 + 64) ^ sx;
            bf16x8 bh0 = *(const bf16x8*)(lbh + s0);
            bf16x8 bh1 = *(const bf16x8*)(lbh + s1);
            bf16x8 bm0 = *(const bf16x8*)(lbm + s0);
            bf16x8 bm1 = *(const bf16x8*)(lbm + s1);
#pragma unroll
            for (int set = 0; set < 2; ++set) {
                f32x4 a = {0.f, 0.f, 0.f, 0.f}, b = {0.f, 0.f, 0.f, 0.f};
                a = __builtin_amdgcn_mfma_f32_16x16x32_bf16(Ah[set][0].v, bh0, a, 0, 0, 0);
                a = __builtin_amdgcn_mfma_f32_16x16x32_bf16(Ah[set][0].v, bm0, a, 0, 0, 0);
                a = __builtin_amdgcn_mfma_f32_16x16x32_bf16(Am[set][0].v, bh0, a, 0, 0, 0);
                b = __builtin_amdgcn_mfma_f32_16x16x32_bf16(Ah[set][1].v, bh1, b, 0, 0, 0);
                b = __builtin_amdgcn_mfma_f32_16x16x32_bf16(Ah[set][1].v, bm1, b, 0, 0, 0);
                b = __builtin_amdgcn_mfma_f32_16x16x32_bf16(Am[set][1].v, bh1, b, 0, 0, 0);
#pragma unroll
                for (int r = 0; r < 4; ++r) {     // D: col=lc, row=lg*4+r (m89)
                    float v = (a[r] + b[r]) - cnv;
                    m2[set][r] = fmaxf(m2[set][r], fminf(m1[set][r], v));
                    if (v > m1[set][r]) { m1[set][r] = v; ix[set][r] = eidx; }
                }
            }
        }
        __syncthreads();
    }

#pragma unroll
    for (int set = 0; set < 2; ++set)
#pragma unroll
        for (int r = 0; r < 4; ++r) {
            float v1 = m1[set][r], v2 = m2[set][r]; int i1 = ix[set][r];
#pragma unroll
            for (int st = 1; st < 16; st <<= 1) {
                float o1 = __shfl_xor(v1, st, 16);
                float o2 = __shfl_xor(v2, st, 16);
                int   oi = __shfl_xor(i1, st, 16);
                float mn = fminf(v1, o1);
                v2 = fmaxf(fmaxf(v2, o2), mn);
                if (o1 > v1 || (o1 == v1 && oi < i1)) { v1 = o1; i1 = oi; }
            }
            if (lc == 0) {
                int vox = vb * 128 + w * 32 + set * 16 + lg * 4 + r;
                res[(size_t)qh * NVOX + vox] =
                    make_float4(v1, v2, __int_as_float(i1), 0.f);
            }
        }
}

// combine 4 quarter-results -> packed (idx | flag<<31) into the IDX slot
__global__ void combine_kernel(const float4* __restrict__ res, float* __restrict__ out) {
    int vox = blockIdx.x * blockDim.x + threadIdx.x;
    float v1 = -INFINITY, v2 = -INFINITY; int idx = 0;
#pragma unroll
    for (int h = 0; h < 4; ++h) {
        float4 t4 = res[(size_t)h * NVOX + vox];
        float a1 = t4.x, a2 = t4.y; int ai = __float_as_int(t4.z);
        float mn = fminf(v1, a1);
        v2 = fmaxf(fmaxf(v2, a2), mn);
        if (a1 > v1) { v1 = a1; idx = ai; }   // strict >: earlier quarter wins ties
    }
    unsigned flag = (v1 - v2 < CERT_EPS) ? 0x80000000u : 0u;
    ((unsigned*)out)[OFF_IDX + vox] = (unsigned)idx | flag;
}

__global__ void gather_kernel(const float* __restrict__ z, const int* __restrict__ zc,
        const float* __restrict__ cb, float* __restrict__ out,
        unsigned* __restrict__ counts, float* __restrict__ sqsum,
        unsigned* __restrict__ list, unsigned* __restrict__ lcount) {
    int vox = blockIdx.x * blockDim.x + threadIdx.x;
    unsigned pk = ((unsigned*)out)[OFF_IDX + vox];
    float s = 0.f;
    if (pk & 0x80000000u) {
        unsigned pos = atomicAdd(lcount, 1u);
        list[pos] = vox;                       // repair kernels finish this row
    } else {
        unsigned idx = pk;
        const float4* crow = (const float4*)(cb + (size_t)idx * DIM);
        const float4* zrow = (const float4*)(z + (size_t)vox * DIM);
        float4* qrow = (float4*)(out + OFF_Q + (size_t)vox * DIM);
#pragma unroll
        for (int i = 0; i < DIM / 4; ++i) {
            float4 c4 = crow[i];
            float4 z4 = zrow[i];
            float dx = z4.x - c4.x, dy = z4.y - c4.y;
            float dz = z4.z - c4.z, dw = z4.w - c4.w;
            s += dx * dx + dy * dy + dz * dz + dw * dw;
            qrow[i] = c4;
        }
        out[OFF_IDX + vox] = (float)idx;
        atomicAdd(&counts[zc[vox * 4] * NUM_EMB + idx], 1u);
    }
#pragma unroll
    for (int o = 32; o > 0; o >>= 1) s += __shfl_down(s, o, 64);
    __shared__ float red[TPB / 64];
    if ((threadIdx.x & 63) == 0) red[threadIdx.x >> 6] = s;
    __syncthreads();
    if (threadIdx.x == 0)
        atomicAdd(sqsum, red[0] + red[1] + red[2] + red[3]);
}

// Repair scan (r6 fix): work item = (flagged row, 512-entry chunk); 2048 waves
// grid-stride -> per-wave serial length 128 groups (was 2048). Unroll x4 with
// interleaved 16-lane reduce chains (4-deep, not 16-deep). Exact f32 dists are
// bit-identical across waves (same slice + reduce order), merged via packed
// (sortable_dist<<32)|idx u64 atomicMin -> lowest-index tie-break preserved.
__global__ void repair_scan_kernel(const float* __restrict__ z,
        const float* __restrict__ cb, const unsigned* __restrict__ list,
        const unsigned* __restrict__ lcount,
        unsigned long long* __restrict__ merge) {
    int wid = (blockIdx.x * blockDim.x + threadIdx.x) >> 6;
    int l   = threadIdx.x & 63;
    int nw  = (gridDim.x * blockDim.x) >> 6;
    int nitems = (int)*lcount * (NUM_EMB / RCH);
    int sub = l & 15, ent = l >> 4;

    for (int it = wid; it < nitems; it += nw) {
        int k    = it / (NUM_EMB / RCH);
        int base = (it % (NUM_EMB / RCH)) * RCH;
        int vox  = list[k];
        float4 z4 = ((const float4*)(z + (size_t)vox * DIM))[sub];
        float m = INFINITY; int mi = 0;

        for (int g0 = 0; g0 < RCH / 4; g0 += 4) {
            float d[4];
#pragma unroll
            for (int u = 0; u < 4; ++u) {
                int e = base + (g0 + u) * 4 + ent;
                float4 c4 = ((const float4*)(cb + (size_t)e * DIM))[sub];
                float dx = z4.x - c4.x, dy = z4.y - c4.y;
                float dz = z4.z - c4.z, dw = z4.w - c4.w;
                d[u] = fmaf(dx, dx, fmaf(dy, dy, fmaf(dz, dz, dw * dw)));
            }
#pragma unroll
            for (int st = 1; st < 16; st <<= 1)     // 4 independent chains
#pragma unroll
                for (int u = 0; u < 4; ++u) d[u] += __shfl_xor(d[u], st, 16);
#pragma unroll
            for (int u = 0; u < 4; ++u) {
                int e = base + (g0 + u) * 4 + ent;
                if (d[u] < m) { m = d[u]; mi = e; }  // ascending e: lowest-idx
            }
        }
#pragma unroll
        for (int st = 32; st > 0; st >>= 1) {
            float om = __shfl_xor(m, st, 64);
            int   oi = __shfl_xor(mi, st, 64);
            if (om < m || (om == m && oi < mi)) { m = om; mi = oi; }
        }
        if (l == 0) {
            unsigned long long key =
                ((unsigned long long)fmap(m) << 32) | (unsigned)mi;
            atomicMin(&merge[vox], key);
        }
    }
}

// apply repaired argmin: Q row, idx, counts, sqsum for flagged rows
__global__ void repair_apply_kernel(const float* __restrict__ z,
        const int* __restrict__ zc, const float* __restrict__ cb,
        const unsigned* __restrict__ list, const unsigned* __restrict__ lcount,
        const unsigned long long* __restrict__ merge, float* __restrict__ out,
        unsigned* __restrict__ counts, float* __restrict__ sqsum) {
    int wid = (blockIdx.x * blockDim.x + threadIdx.x) >> 6;
    int l   = threadIdx.x & 63;
    int n   = (int)*lcount;
    int nw  = (gridDim.x * blockDim.x) >> 6;
    for (int k = wid; k < n; k += nw) {
        int vox = list[k];
        int mi  = (int)(merge[vox] & 0xFFFFFFFFull);
        float cv = cb[(size_t)mi * DIM + l];
        float zv = z[(size_t)vox * DIM + l];
        out[OFF_Q + (size_t)vox * DIM + l] = cv;
        float df = zv - cv;
        float s = df * df;
#pragma unroll
        for (int st = 32; st > 0; st >>= 1) s += __shfl_xor(s, st, 64);
        if (l == 0) {
            out[OFF_IDX + vox] = (float)mi;
            atomicAdd(&counts[zc[vox * 4] * NUM_EMB + mi], 1u);
            atomicAdd(sqsum, s);
        }
    }
}

__global__ void stats_kernel(const unsigned* __restrict__ counts, float* __restrict__ stats) {
    int b = blockIdx.x;
    const unsigned* c = counts + b * NUM_EMB;

    __shared__ float sred[TPB / 64];
    float nf = 0.f;
    for (int i = threadIdx.x; i < NUM_EMB; i += TPB) nf += (float)c[i];
#pragma unroll
    for (int o = 32; o > 0; o >>= 1) nf += __shfl_down(nf, o, 64);
    if ((threadIdx.x & 63) == 0) sred[threadIdx.x >> 6] = nf;
    __syncthreads();
    float n = sred[0] + sred[1] + sred[2] + sred[3];
    __syncthreads();

    float ent = 0.f, uniq = 0.f;
    for (int i = threadIdx.x; i < NUM_EMB; i += TPB) {
        unsigned ci = c[i];
        if (ci) {
            float p = (float)ci / n;
            ent -= p * logf(p + 1e-10f);
            uniq += 1.f;
        }
    }
#pragma unroll
    for (int o = 32; o > 0; o >>= 1) {
        ent  += __shfl_down(ent, o, 64);
        uniq += __shfl_down(uniq, o, 64);
    }
    __shared__ float e4[TPB / 64], u4[TPB / 64];
    if ((threadIdx.x & 63) == 0) { e4[threadIdx.x >> 6] = ent; u4[threadIdx.x >> 6] = uniq; }
    __syncthreads();
    if (threadIdx.x == 0) {
        stats[b]     = e4[0] + e4[1] + e4[2] + e4[3];
        stats[4 + b] = u4[0] + u4[1] + u4[2] + u4[3];
    }
}

__global__ void finalize_kernel(const float* __restrict__ stats,
                                const float* __restrict__ sqsum,
                                float* __restrict__ out) {
    float loss = *sqsum / (float)((size_t)NVOX * DIM);
    float ae = 0.f, ap = 0.f, au = 0.f;
#pragma unroll
    for (int b = 0; b < NBATCH; ++b) {
        ae += stats[b];
        ap += expf(stats[b]);
        au += stats[4 + b];
    }
    ae *= (1.f / NBATCH); ap *= (1.f / NBATCH); au *= (1.f / NBATCH);
    out[OFF_VQ]   = loss;
    out[OFF_COMM] = loss;
    out[OFF_PERP] = ap;
    out[OFF_ENT]  = ae;
    out[OFF_UNIQ] = au;
    out[OFF_UTIL] = au / (float)NUM_EMB * 100.f;
}

extern "C" void kernel_launch(void* const* d_in, const int* in_sizes, int n_in,
                              void* d_out, int out_size, void* d_ws, size_t ws_size,
                              hipStream_t stream) {
    const float* z  = (const float*)d_in[0];
    const int*   zc = (const int*)d_in[1];
    const float* cb = (const float*)d_in[2];
    float* out = (float*)d_out;
    char* ws = (char*)d_ws;

    // scratch in the d_out Q-region (8MB): cbh 1MB | cbm 1MB | res 2MB.
    // (merge CANNOT alias Q: gather writes Q rows concurrently -> ws only.)
    unsigned short* cbh = (unsigned short*)out;
    unsigned short* cbm = cbh + NUM_EMB * DIM;
    float4* res = (float4*)(out + 524288);

    unsigned* counts = (unsigned*)ws;                       // 131072 B
    unsigned* list   = (unsigned*)(ws + 131072);            // 131072 B
    unsigned* lcount = (unsigned*)(ws + 262144);            // 4 B
    float*    sqsum  = (float*)(ws + 262148);               // 4 B
    float*    stats  = (float*)(ws + 262152);               // 32 B
    float*    cnh    = (float*)(ws + 262184);               // 32768 B
    unsigned long long* merge = (unsigned long long*)(ws + 294952); // 262144 B

    hipMemsetAsync(counts, 0, 131072, stream);
    hipMemsetAsync(lcount, 0, 40, stream);                  // lcount+sqsum+stats
    hipMemsetAsync(merge, 0xFF, 262144, stream);            // u64 max sentinel

    prep_kernel<<<NUM_EMB / 4, TPB, 0, stream>>>(cb, cbh, cbm, cnh);
    argmin_kernel<<<(NVOX / 128) * 4, TPB, 0, stream>>>(z, cbh, cbm, cnh, res);
    combine_kernel<<<NVOX / TPB, TPB, 0, stream>>>(res, out);
    gather_kernel<<<NVOX / TPB, TPB, 0, stream>>>(z, zc, cb, out, counts, sqsum,
                                                  list, lcount);
    repair_scan_kernel<<<512, TPB, 0, stream>>>(z, cb, list, lcount, merge);
    repair_apply_kernel<<<64, TPB, 0, stream>>>(z, zc, cb, list, lcount, merge,
                                                out, counts, sqsum);
    stats_kernel<<<NBATCH, TPB, 0, stream>>>(counts, stats);
    finalize_kernel<<<1, 1, 0, stream>>>(stats, sqsum, out);
}

// Round 8
// 200.117 us; speedup vs baseline: 3.5188x; 1.2047x over previous
//
#include <hip/hip_runtime.h>
#include <math.h>

#define NUM_EMB 8192
#define DIM     64
#define NBATCH  4
#define NVOX    32768
#define TPB     256
#define QENT    2048              // entries per block (quarter codebook)
#define CHUNK   128               // entries staged per iteration
#define CERT_EPS 0.015f           // v-space gap threshold (err bound ~3.2e-3)
#define RCH     512               // repair: entries per (row,chunk) work item

// output layout (f32, concatenated in return order)
#define OFF_Q     0            // 32768*64
#define OFF_VQ    2097152
#define OFF_COMM  2097153
#define OFF_IDX   2097154      // 32768
#define OFF_PERP  2129922
#define OFF_ENT   2129923
#define OFF_UNIQ  2129924
#define OFF_UTIL  2129925

typedef __bf16 bf16x8 __attribute__((ext_vector_type(8)));
typedef float  f32x4  __attribute__((ext_vector_type(4)));

__device__ __forceinline__ unsigned short f2bf(float f) {   // RNE f32->bf16
    unsigned u = __float_as_uint(f);
    unsigned r = u + 0x7FFFu + ((u >> 16) & 1u);
    return (unsigned short)(r >> 16);
}
__device__ __forceinline__ float bf2f(unsigned short h) {
    return __uint_as_float(((unsigned)h) << 16);
}
// monotone float -> sortable uint (non-NaN)
__device__ __forceinline__ unsigned fmap(float f) {
    unsigned u = __float_as_uint(f);
    return (u & 0x80000000u) ? ~u : (u | 0x80000000u);
}

// prep: bf16 2-split of codebook, replicated -||c||^2/2 (MFMA C-init quad),
// plus ALL scratch init (counts, merge sentinels, lcount/sqsum) -> no memsets.
__global__ void prep_kernel(const float* __restrict__ cb,
                            unsigned short* __restrict__ cbh,
                            unsigned short* __restrict__ cbm,
                            float* __restrict__ cnp4,
                            unsigned* __restrict__ counts,
                            unsigned* __restrict__ misc,
                            unsigned long long* __restrict__ merge) {
    int row = blockIdx.x * 4 + (threadIdx.x >> 6);
    int l   = threadIdx.x & 63;
    float f = cb[row * DIM + l];
    unsigned short hh = f2bf(f); float r1 = f - bf2f(hh);
    cbh[row * DIM + l] = hh;
    cbm[row * DIM + l] = f2bf(r1);
    float s = f * f;
#pragma unroll
    for (int o = 32; o > 0; o >>= 1) s += __shfl_xor(s, o, 64);
    if (l < 4) cnp4[row * 4 + l] = -0.5f * s;      // replicated x4 -> b128 C-init

    int gid = blockIdx.x * TPB + threadIdx.x;       // 0..524287
    if (gid < NBATCH * NUM_EMB) counts[gid] = 0;
    if (gid >= 32768 && gid < 65536) merge[gid - 32768] = ~0ull;
    if (gid < 16) misc[gid] = 0;                    // lcount, sqsum, pad
}

// Single-pass 3-product (hh,hm,mh) MFMA scan. Per tile: C-init = -||c||^2/2
// from one ds_read_b128, 6 chained MFMA per set -> v = acc[r] directly;
// m2 via v_med3_f32; ds addressing = 2 lane bases + compile-time offsets.
__global__ __launch_bounds__(TPB) void argmin_kernel(
        const float* __restrict__ z,
        const unsigned short* __restrict__ cbh,
        const unsigned short* __restrict__ cbm,
        const float* __restrict__ cnp4,
        float4* __restrict__ res) {
    __shared__ __align__(16) char lds[2 * CHUNK * 128 + CHUNK * 16];
    // [0,16K) lbh | [16K,32K) lbm | [32K,34K) cnp4 quads

    const int t  = threadIdx.x;
    const int l  = t & 63, w = t >> 6;
    const int lc = l & 15, lg = l >> 4;
    const int vb = blockIdx.x >> 2, qh = blockIdx.x & 3;
    const int ebase = qh * QENT;

    union U { bf16x8 v; unsigned short s[8]; };
    U Ah[2][2], Am[2][2];                // on-the-fly 2-split of 32 z rows
#pragma unroll
    for (int set = 0; set < 2; ++set) {
        const float* zp = z + (size_t)(vb * 128 + w * 32 + set * 16 + lc) * DIM + lg * 8;
#pragma unroll
        for (int ks = 0; ks < 2; ++ks)
#pragma unroll
            for (int j = 0; j < 8; ++j) {
                float f = zp[ks * 32 + j];
                unsigned short hh = f2bf(f);
                Ah[set][ks].s[j] = hh;
                Am[set][ks].s[j] = f2bf(f - bf2f(hh));
            }
    }

    float m1[2][4], m2[2][4]; int ix[2][4];
#pragma unroll
    for (int set = 0; set < 2; ++set)
#pragma unroll
        for (int r = 0; r < 4; ++r) {
            m1[set][r] = -INFINITY; m2[set][r] = -INFINITY; ix[set][r] = 0;
        }

    // per-lane LDS bases: XOR-swizzle folded once; k-step1 = base ^ 64
    // (valid: pre-XOR addr bit6 = 0 since lg*16 < 64)
    const int b0 = (lc * 128 + lg * 16) ^ ((lc & 7) << 4);
    const int b1 = b0 ^ 64;
    const int cb0 = 2 * CHUNK * 128 + lc * 16;

    for (int ch = 0; ch < QENT / CHUNK; ++ch) {
        const char* sh = (const char*)cbh + (size_t)(ebase + ch * CHUNK) * 128;
        const char* sm = (const char*)cbm + (size_t)(ebase + ch * CHUNK) * 128;
#pragma unroll
        for (int j = 0; j < 4; ++j) {            // XOR-swizzle (row&7)<<4
            int off = (j * 256 + t) * 16;
            int swz = off ^ (((off >> 7) & 7) << 4);
            *(uint4*)(lds + swz) = *(const uint4*)(sh + off);
            *(uint4*)(lds + 16384 + swz) = *(const uint4*)(sm + off);
        }
        if (t < CHUNK)
            ((float4*)(lds + 2 * CHUNK * 128))[t] =
                ((const float4*)cnp4)[ebase + ch * CHUNK + t];
        __syncthreads();

        int e0 = ebase + ch * CHUNK + lc;
#pragma unroll 4
        for (int tile = 0; tile < CHUNK / 16; ++tile) {
            bf16x8 bh0 = *(const bf16x8*)(lds + b0 + tile * 2048);
            bf16x8 bh1 = *(const bf16x8*)(lds + b1 + tile * 2048);
            bf16x8 bm0 = *(const bf16x8*)(lds + 16384 + b0 + tile * 2048);
            bf16x8 bm1 = *(const bf16x8*)(lds + 16384 + b1 + tile * 2048);
            f32x4  c0  = *(const f32x4*)(lds + cb0 + tile * 256);
            int eidx = e0 + tile * 16;
#pragma unroll
            for (int set = 0; set < 2; ++set) {
                f32x4 a = c0;                     // C-init = -||c||^2/2 (free)
                a = __builtin_amdgcn_mfma_f32_16x16x32_bf16(Ah[set][0].v, bh0, a, 0, 0, 0);
                a = __builtin_amdgcn_mfma_f32_16x16x32_bf16(Am[set][0].v, bh0, a, 0, 0, 0);
                a = __builtin_amdgcn_mfma_f32_16x16x32_bf16(Ah[set][0].v, bm0, a, 0, 0, 0);
                a = __builtin_amdgcn_mfma_f32_16x16x32_bf16(Ah[set][1].v, bh1, a, 0, 0, 0);
                a = __builtin_amdgcn_mfma_f32_16x16x32_bf16(Am[set][1].v, bh1, a, 0, 0, 0);
                a = __builtin_amdgcn_mfma_f32_16x16x32_bf16(Ah[set][1].v, bm1, a, 0, 0, 0);
#pragma unroll
                for (int r = 0; r < 4; ++r) {     // D: col=lc, row=lg*4+r (m89)
                    float v = a[r];               // = z.c - ||c||^2/2 exactly
                    m2[set][r] = __builtin_amdgcn_fmed3f(v, m1[set][r], m2[set][r]);
                    if (v > m1[set][r]) { m1[set][r] = v; ix[set][r] = eidx; }
                }
            }
        }
        __syncthreads();
    }

    // reduce (max1,idx,max2) across the 16 column-lanes, lowest-idx tiebreak
#pragma unroll
    for (int set = 0; set < 2; ++set)
#pragma unroll
        for (int r = 0; r < 4; ++r) {
            float v1 = m1[set][r], v2 = m2[set][r]; int i1 = ix[set][r];
#pragma unroll
            for (int st = 1; st < 16; st <<= 1) {
                float o1 = __shfl_xor(v1, st, 16);
                float o2 = __shfl_xor(v2, st, 16);
                int   oi = __shfl_xor(i1, st, 16);
                float mn = fminf(v1, o1);
                v2 = fmaxf(fmaxf(v2, o2), mn);
                if (o1 > v1 || (o1 == v1 && oi < i1)) { v1 = o1; i1 = oi; }
            }
            if (lc == 0) {
                int vox = vb * 128 + w * 32 + set * 16 + lg * 4 + r;
                res[(size_t)qh * NVOX + vox] =
                    make_float4(v1, v2, __int_as_float(i1), 0.f);
            }
        }
}

// combine 4 quarter-results -> packed (idx | flag<<31) into the IDX slot;
// also zeroes the 6 scalar outputs (poisoned 0xAA) for stats' atomicAdds.
__global__ void combine_kernel(const float4* __restrict__ res, float* __restrict__ out) {
    int vox = blockIdx.x * blockDim.x + threadIdx.x;
    float v1 = -INFINITY, v2 = -INFINITY; int idx = 0;
#pragma unroll
    for (int h = 0; h < 4; ++h) {
        float4 t4 = res[(size_t)h * NVOX + vox];
        float a1 = t4.x, a2 = t4.y; int ai = __float_as_int(t4.z);
        float mn = fminf(v1, a1);
        v2 = fmaxf(fmaxf(v2, a2), mn);
        if (a1 > v1) { v1 = a1; idx = ai; }   // strict >: earlier quarter wins ties
    }
    unsigned flag = (v1 - v2 < CERT_EPS) ? 0x80000000u : 0u;
    ((unsigned*)out)[OFF_IDX + vox] = (unsigned)idx | flag;
    if (vox == 0) {
        out[OFF_VQ] = 0.f; out[OFF_COMM] = 0.f; out[OFF_PERP] = 0.f;
        out[OFF_ENT] = 0.f; out[OFF_UNIQ] = 0.f; out[OFF_UTIL] = 0.f;
    }
}

__global__ void gather_kernel(const float* __restrict__ z, const int* __restrict__ zc,
        const float* __restrict__ cb, float* __restrict__ out,
        unsigned* __restrict__ counts, float* __restrict__ sqsum,
        unsigned* __restrict__ list, unsigned* __restrict__ lcount) {
    int vox = blockIdx.x * blockDim.x + threadIdx.x;
    unsigned pk = ((unsigned*)out)[OFF_IDX + vox];
    float s = 0.f;
    if (pk & 0x80000000u) {
        unsigned pos = atomicAdd(lcount, 1u);
        list[pos] = vox;                       // repair kernels finish this row
    } else {
        unsigned idx = pk;
        const float4* crow = (const float4*)(cb + (size_t)idx * DIM);
        const float4* zrow = (const float4*)(z + (size_t)vox * DIM);
        float4* qrow = (float4*)(out + OFF_Q + (size_t)vox * DIM);
#pragma unroll
        for (int i = 0; i < DIM / 4; ++i) {
            float4 c4 = crow[i];
            float4 z4 = zrow[i];
            float dx = z4.x - c4.x, dy = z4.y - c4.y;
            float dz = z4.z - c4.z, dw = z4.w - c4.w;
            s += dx * dx + dy * dy + dz * dz + dw * dw;
            qrow[i] = c4;
        }
        out[OFF_IDX + vox] = (float)idx;
        atomicAdd(&counts[zc[vox * 4] * NUM_EMB + idx], 1u);
    }
#pragma unroll
    for (int o = 32; o > 0; o >>= 1) s += __shfl_down(s, o, 64);
    __shared__ float red[TPB / 64];
    if ((threadIdx.x & 63) == 0) red[threadIdx.x >> 6] = s;
    __syncthreads();
    if (threadIdx.x == 0)
        atomicAdd(sqsum, red[0] + red[1] + red[2] + red[3]);
}

// Repair scan: (flagged row, 512-entry chunk) work items over 2048 waves;
// coalesced 4-entry groups, x4 interleaved reduce chains; exact f32 dists
// merged via packed (sortable<<32)|idx u64 atomicMin (lowest-idx ties).
__global__ void repair_scan_kernel(const float* __restrict__ z,
        const float* __restrict__ cb, const unsigned* __restrict__ list,
        const unsigned* __restrict__ lcount,
        unsigned long long* __restrict__ merge) {
    int wid = (blockIdx.x * blockDim.x + threadIdx.x) >> 6;
    int l   = threadIdx.x & 63;
    int nw  = (gridDim.x * blockDim.x) >> 6;
    int nitems = (int)*lcount * (NUM_EMB / RCH);
    int sub = l & 15, ent = l >> 4;

    for (int it = wid; it < nitems; it += nw) {
        int k    = it / (NUM_EMB / RCH);
        int base = (it % (NUM_EMB / RCH)) * RCH;
        int vox  = list[k];
        float4 z4 = ((const float4*)(z + (size_t)vox * DIM))[sub];
        float m = INFINITY; int mi = 0;

        for (int g0 = 0; g0 < RCH / 4; g0 += 4) {
            float d[4];
#pragma unroll
            for (int u = 0; u < 4; ++u) {
                int e = base + (g0 + u) * 4 + ent;
                float4 c4 = ((const float4*)(cb + (size_t)e * DIM))[sub];
                float dx = z4.x - c4.x, dy = z4.y - c4.y;
                float dz = z4.z - c4.z, dw = z4.w - c4.w;
                d[u] = fmaf(dx, dx, fmaf(dy, dy, fmaf(dz, dz, dw * dw)));
            }
#pragma unroll
            for (int st = 1; st < 16; st <<= 1)     // 4 independent chains
#pragma unroll
                for (int u = 0; u < 4; ++u) d[u] += __shfl_xor(d[u], st, 16);
#pragma unroll
            for (int u = 0; u < 4; ++u) {
                int e = base + (g0 + u) * 4 + ent;
                if (d[u] < m) { m = d[u]; mi = e; }  // ascending e: lowest-idx
            }
        }
#pragma unroll
        for (int st = 32; st > 0; st >>= 1) {
            float om = __shfl_xor(m, st, 64);
            int   oi = __shfl_xor(mi, st, 64);
            if (om < m || (om == m && oi < mi)) { m = om; mi = oi; }
        }
        if (l == 0) {
            unsigned long long key =
                ((unsigned long long)fmap(m) << 32) | (unsigned)mi;
            atomicMin(&merge[vox], key);
        }
    }
}

// apply repaired argmin: Q row, idx, counts, sqsum for flagged rows
__global__ void repair_apply_kernel(const float* __restrict__ z,
        const int* __restrict__ zc, const float* __restrict__ cb,
        const unsigned* __restrict__ list, const unsigned* __restrict__ lcount,
        const unsigned long long* __restrict__ merge, float* __restrict__ out,
        unsigned* __restrict__ counts, float* __restrict__ sqsum) {
    int wid = (blockIdx.x * blockDim.x + threadIdx.x) >> 6;
    int l   = threadIdx.x & 63;
    int n   = (int)*lcount;
    int nw  = (gridDim.x * blockDim.x) >> 6;
    for (int k = wid; k < n; k += nw) {
        int vox = list[k];
        int mi  = (int)(merge[vox] & 0xFFFFFFFFull);
        float cv = cb[(size_t)mi * DIM + l];
        float zv = z[(size_t)vox * DIM + l];
        out[OFF_Q + (size_t)vox * DIM + l] = cv;
        float df = zv - cv;
        float s = df * df;
#pragma unroll
        for (int st = 32; st > 0; st >>= 1) s += __shfl_xor(s, st, 64);
        if (l == 0) {
            out[OFF_IDX + vox] = (float)mi;
            atomicAdd(&counts[zc[vox * 4] * NUM_EMB + mi], 1u);
            atomicAdd(sqsum, s);
        }
    }
}

// per-batch entropy/unique + fused finalize via atomicAdd on zeroed scalars
__global__ void stats_final_kernel(const unsigned* __restrict__ counts,
                                   const float* __restrict__ sqsum,
                                   float* __restrict__ out) {
    int b = blockIdx.x;
    const unsigned* c = counts + b * NUM_EMB;

    __shared__ float sred[TPB / 64];
    float nf = 0.f;
    for (int i = threadIdx.x; i < NUM_EMB; i += TPB) nf += (float)c[i];
#pragma unroll
    for (int o = 32; o > 0; o >>= 1) nf += __shfl_down(nf, o, 64);
    if ((threadIdx.x & 63) == 0) sred[threadIdx.x >> 6] = nf;
    __syncthreads();
    float n = sred[0] + sred[1] + sred[2] + sred[3];
    __syncthreads();

    float ent = 0.f, uniq = 0.f;
    for (int i = threadIdx.x; i < NUM_EMB; i += TPB) {
        unsigned ci = c[i];
        if (ci) {
            float p = (float)ci / n;
            ent -= p * logf(p + 1e-10f);
            uniq += 1.f;
        }
    }
#pragma unroll
    for (int o = 32; o > 0; o >>= 1) {
        ent  += __shfl_down(ent, o, 64);
        uniq += __shfl_down(uniq, o, 64);
    }
    __shared__ float e4[TPB / 64], u4[TPB / 64];
    if ((threadIdx.x & 63) == 0) { e4[threadIdx.x >> 6] = ent; u4[threadIdx.x >> 6] = uniq; }
    __syncthreads();
    if (threadIdx.x == 0) {
        float eb = e4[0] + e4[1] + e4[2] + e4[3];
        float ub = u4[0] + u4[1] + u4[2] + u4[3];
        atomicAdd(&out[OFF_ENT],  eb * 0.25f);
        atomicAdd(&out[OFF_PERP], expf(eb) * 0.25f);
        atomicAdd(&out[OFF_UNIQ], ub * 0.25f);
        atomicAdd(&out[OFF_UTIL], ub * (100.f / (4.f * NUM_EMB)));
        if (b == 0) {
            float loss = *sqsum / (float)((size_t)NVOX * DIM);
            out[OFF_VQ]   = loss;
            out[OFF_COMM] = loss;
        }
    }
}

extern "C" void kernel_launch(void* const* d_in, const int* in_sizes, int n_in,
                              void* d_out, int out_size, void* d_ws, size_t ws_size,
                              hipStream_t stream) {
    const float* z  = (const float*)d_in[0];
    const int*   zc = (const int*)d_in[1];
    const float* cb = (const float*)d_in[2];
    float* out = (float*)d_out;
    char* ws = (char*)d_ws;

    // d_out Q-region scratch (8MB): cbh 1MB | cbm 1MB | res 2MB; gather/apply
    // fully overwrite Q afterwards. combine stays a separate kernel: fusing it
    // with gather would race res reads vs Q writes (vox 8192..16383 alias res).
    unsigned short* cbh = (unsigned short*)out;
    unsigned short* cbm = cbh + NUM_EMB * DIM;
    float4* res = (float4*)(out + 524288);

    unsigned* counts = (unsigned*)ws;                       // 131072 B
    unsigned* list   = (unsigned*)(ws + 131072);            // 131072 B
    unsigned* misc   = (unsigned*)(ws + 262144);            // 64 B: lcount,sqsum
    unsigned* lcount = misc;
    float*    sqsum  = (float*)(ws + 262148);
    float*    cnp4   = (float*)(ws + 262208);               // 131072 B (16B-aligned)
    unsigned long long* merge = (unsigned long long*)(ws + 393280); // 262144 B

    prep_kernel<<<NUM_EMB / 4, TPB, 0, stream>>>(cb, cbh, cbm, cnp4,
                                                 counts, misc, merge);
    argmin_kernel<<<(NVOX / 128) * 4, TPB, 0, stream>>>(z, cbh, cbm, cnp4, res);
    combine_kernel<<<NVOX / TPB, TPB, 0, stream>>>(res, out);
    gather_kernel<<<NVOX / TPB, TPB, 0, stream>>>(z, zc, cb, out, counts, sqsum,
                                                  list, lcount);
    repair_scan_kernel<<<512, TPB, 0, stream>>>(z, cb, list, lcount, merge);
    repair_apply_kernel<<<64, TPB, 0, stream>>>(z, zc, cb, list, lcount, merge,
                                                out, counts, sqsum);
    stats_final_kernel<<<NBATCH, TPB, 0, stream>>>(counts, sqsum, out);
}